// Round 8
// baseline (112.666 us; speedup 1.0000x reference)
//
#include <hip/hip_runtime.h>
#include <cstdint>
#include <cstring>

// JAX >= 0.4.36 defaults jax_threefry_partitionable=True (verified bit-exact in R3).
#ifndef THREEFRY_PARTITIONABLE
#define THREEFRY_PARTITIONABLE 1
#endif

static constexpr int B_ = 16, C_ = 64, H_ = 256, W_ = 256;
static constexpr uint32_t CHW = (uint32_t)C_ * H_ * W_;            // 4,194,304 floats/sample
static constexpr uint32_t BLOCKS_PER_SAMPLE = 2048;                 // 512 patches/block

// Threefry-2x32, 20 rounds — exact JAX implementation.
__host__ __device__ __forceinline__ void tf2x32(uint32_t k0, uint32_t k1,
                                                uint32_t c0, uint32_t c1,
                                                uint32_t& o0, uint32_t& o1) {
  const uint32_t ks2 = k0 ^ k1 ^ 0x1BD11BDAu;
  uint32_t x0 = c0 + k0, x1 = c1 + k1;
#define TFR(r) { x0 += x1; x1 = (x1 << (r)) | (x1 >> (32 - (r))); x1 ^= x0; }
  TFR(13) TFR(15) TFR(26) TFR(6)
  x0 += k1;  x1 += ks2 + 1u;
  TFR(17) TFR(29) TFR(16) TFR(24)
  x0 += ks2; x1 += k0 + 2u;
  TFR(13) TFR(15) TFR(26) TFR(6)
  x0 += k0;  x1 += k1 + 3u;
  TFR(17) TFR(29) TFR(16) TFR(24)
  x0 += k1;  x1 += ks2 + 4u;
  TFR(13) TFR(15) TFR(26) TFR(6)
  x0 += ks2; x1 += k0 + 5u;
#undef TFR
  o0 = x0; o1 = x1;
}

// random_bits(kperm, 32, (2^26,))[j], partitionable: counter=(0,j), bits=w0^w1
__device__ __forceinline__ uint32_t perm_bits(uint32_t kp0, uint32_t kp1, uint32_t j) {
  uint32_t w0, w1;
#if THREEFRY_PARTITIONABLE
  tf2x32(kp0, kp1, 0u, j, w0, w1);
  return w0 ^ w1;
#else
  uint32_t lo = j & 0x01FFFFFFu;
  tf2x32(kp0, kp1, lo, lo + 0x02000000u, w0, w1);
  return (j < 0x02000000u) ? w0 : w1;
#endif
}

// Stable argsort of 4 keys; scatter v[i] to output slot rank[i].
// Keys are bits>>9 (monotone-equal to the float uniforms, incl. exact ties).
__device__ __forceinline__ void shuffle4(const float v[4], const uint32_t s[4], float o[4]) {
  int r0 = 0, r1 = 0, r2 = 0, r3 = 0;
  if (s[1] < s[0]) r0++; else r1++;
  if (s[2] < s[0]) r0++; else r2++;
  if (s[3] < s[0]) r0++; else r3++;
  if (s[2] < s[1]) r1++; else r2++;
  if (s[3] < s[1]) r1++; else r3++;
  if (s[3] < s[2]) r2++; else r3++;
  o[0] = (r0 == 0) ? v[0] : (r1 == 0) ? v[1] : (r2 == 0) ? v[2] : v[3];
  o[1] = (r0 == 1) ? v[0] : (r1 == 1) ? v[1] : (r2 == 1) ? v[2] : v[3];
  o[2] = (r0 == 2) ? v[0] : (r1 == 2) ? v[1] : (r2 == 2) ? v[2] : v[3];
  o[3] = (r0 == 3) ? v[0] : (r1 == 3) ? v[1] : (r2 == 3) ? v[2] : v[3];
}

__device__ __forceinline__ void shuffle_patch(uint32_t kp0, uint32_t kp1, uint32_t patch,
                                              float p0, float p1, float p2, float p3,
                                              float o[4]) {
  const uint32_t jbase = patch << 2;
  uint32_t s[4];
#pragma unroll
  for (int p = 0; p < 4; ++p) s[p] = perm_bits(kp0, kp1, jbase + (uint32_t)p) >> 9;
  const float v[4] = {p0, p1, p2, p3};
  shuffle4(v, s, o);
}

// Shuffle-only kernel: launched ONLY over shuffled samples (ids packed 4b each
// in `ids`). Unshuffled samples are copied by vendor hipMemcpyAsync D2D nodes.
// Body = R3's proven 2-patch/thread structure, branch-free.
__global__ __launch_bounds__(256) void PatchShuffle_26869315404121_kernel(
    const float* __restrict__ x, float* __restrict__ out,
    uint32_t kp0, uint32_t kp1, uint64_t ids) {
  const uint32_t bid    = blockIdx.x;
  const uint32_t widx   = bid >> 11;                        // which shuffled sample
  const uint32_t sample = (uint32_t)((ids >> (4u * widx)) & 15u);
  const uint32_t chunk  = bid & (BLOCKS_PER_SAMPLE - 1u);   // [0, 2048)
  const uint32_t gid    = (sample << 20) | (chunk << 9) | (threadIdx.x << 1);

  const uint32_t wp   = gid & 127u;             // even
  const uint32_t rest = gid >> 7;               // (b*C+c)*Hp + hp
  const uint32_t base = rest * 512u + wp * 2u;  // 4 cols x 2 rows, 16B aligned

  const float4 r0 = *reinterpret_cast<const float4*>(x + base);       // row 2*hp
  const float4 r1 = *reinterpret_cast<const float4*>(x + base + W_);  // row 2*hp+1
  float4* d0 = reinterpret_cast<float4*>(out + base);
  float4* d1 = reinterpret_cast<float4*>(out + base + W_);

  // patch pixel order p = ph*2+pw: [row0.c0, row0.c1, row1.c0, row1.c1]
  float oA[4], oB[4];
  shuffle_patch(kp0, kp1, gid + 0u, r0.x, r0.y, r1.x, r1.y, oA);
  shuffle_patch(kp0, kp1, gid + 1u, r0.z, r0.w, r1.z, r1.w, oB);
  *d0 = make_float4(oA[0], oA[1], oB[0], oB[1]);
  *d1 = make_float4(oA[2], oA[3], oB[2], oB[3]);
}

extern "C" void kernel_launch(void* const* d_in, const int* in_sizes, int n_in,
                              void* d_out, int out_size, void* d_ws, size_t ws_size,
                              hipStream_t stream) {
  const float* x = (const float*)d_in[0];
  float* out = (float*)d_out;

  // ---- host-side PRNG (pure arithmetic, deterministic, capture-safe) ----
  const uint32_t k0 = 0u, k1 = 42u;  // jax.random.key(42) -> [0, 42]
  uint32_t km0, km1, kp0, kp1;
#if THREEFRY_PARTITIONABLE
  tf2x32(k0, k1, 0u, 0u, km0, km1);  // split fold-like: kmask = TF(key,(0,0))
  tf2x32(k0, k1, 0u, 1u, kp0, kp1);  //                  kperm = TF(key,(0,1))
#else
  {
    uint32_t a0, a1, b0v, b1v;
    tf2x32(k0, k1, 0u, 2u, a0, a1);
    tf2x32(k0, k1, 1u, 3u, b0v, b1v);
    km0 = a0; km1 = b0v;
    kp0 = a1; kp1 = b1v;
  }
#endif

  uint32_t maskbits = 0u;
  for (uint32_t s = 0; s < 16u; ++s) {
    uint32_t w0, w1, bits;
#if THREEFRY_PARTITIONABLE
    tf2x32(km0, km1, 0u, s, w0, w1);
    bits = w0 ^ w1;
#else
    uint32_t i = s & 7u;
    tf2x32(km0, km1, i, i + 8u, w0, w1);
    bits = (s < 8u) ? w0 : w1;
#endif
    uint32_t fb = (bits >> 9) | 0x3F800000u;
    float u;
    std::memcpy(&u, &fb, sizeof(u));
    u -= 1.0f;                           // uniform in [0,1)
    if (u < 0.1f) maskbits |= (1u << s); // torch.rand(1) < shuffle_prob
  }

  // ---- split work: vendor D2D memcpy for unshuffled runs, kernel for rest ----
  uint64_t ids = 0;          // packed shuffled-sample indices, 4 bits each
  uint32_t nshuf = 0;
  for (uint32_t s = 0; s < 16u; ++s) {
    if ((maskbits >> s) & 1u) { ids |= ((uint64_t)s) << (4u * nshuf); ++nshuf; }
  }

  // Contiguous runs of unshuffled samples -> one memcpy node per run.
  uint32_t s = 0;
  while (s < 16u) {
    if ((maskbits >> s) & 1u) { ++s; continue; }
    uint32_t e = s;
    while (e < 16u && !((maskbits >> e) & 1u)) ++e;   // [s, e) unshuffled
    const size_t off   = (size_t)s * CHW;
    const size_t bytes = (size_t)(e - s) * CHW * sizeof(float);
    hipMemcpyAsync(out + off, x + off, bytes, hipMemcpyDeviceToDevice, stream);
    s = e;
  }

  if (nshuf > 0) {
    PatchShuffle_26869315404121_kernel<<<nshuf * BLOCKS_PER_SAMPLE, 256, 0, stream>>>(
        x, out, kp0, kp1, ids);
  }
}

// Round 9
// 98.825 us; speedup vs baseline: 1.1401x; 1.1401x over previous
//
#include <hip/hip_runtime.h>
#include <cstdint>
#include <cstring>

// JAX >= 0.4.36 defaults jax_threefry_partitionable=True (verified bit-exact in R3).
#ifndef THREEFRY_PARTITIONABLE
#define THREEFRY_PARTITIONABLE 1
#endif

static constexpr int B_ = 16, C_ = 64, H_ = 256, W_ = 256;
static constexpr int Hp_ = H_ / 2, Wp_ = W_ / 2;
static constexpr uint32_t NPATCH = (uint32_t)B_ * C_ * Hp_ * Wp_;  // 2^24
static constexpr uint32_t NTHREAD = NPATCH / 2;                    // 2^23 (2 patches/thread)

// Final form (R9 = R3 verbatim): 99.3 us, ~5.4 TB/s effective on the 512 MiB
// mixed R/W stream. Tested and rejected: 64B/thread (null), NT stores
// (replay corruption), sample-interleave (-35%), persistent 8blk/CU (-10%),
// vendor hipMemcpyAsync blit for unshuffled samples (-13%). The limiter is
// the coherent read+write fabric path, not HBM (FETCH ~131MB via L3), not
// VALU, not occupancy.

// Threefry-2x32, 20 rounds — exact JAX implementation.
__host__ __device__ __forceinline__ void tf2x32(uint32_t k0, uint32_t k1,
                                                uint32_t c0, uint32_t c1,
                                                uint32_t& o0, uint32_t& o1) {
  const uint32_t ks2 = k0 ^ k1 ^ 0x1BD11BDAu;
  uint32_t x0 = c0 + k0, x1 = c1 + k1;
#define TFR(r) { x0 += x1; x1 = (x1 << (r)) | (x1 >> (32 - (r))); x1 ^= x0; }
  TFR(13) TFR(15) TFR(26) TFR(6)
  x0 += k1;  x1 += ks2 + 1u;
  TFR(17) TFR(29) TFR(16) TFR(24)
  x0 += ks2; x1 += k0 + 2u;
  TFR(13) TFR(15) TFR(26) TFR(6)
  x0 += k0;  x1 += k1 + 3u;
  TFR(17) TFR(29) TFR(16) TFR(24)
  x0 += k1;  x1 += ks2 + 4u;
  TFR(13) TFR(15) TFR(26) TFR(6)
  x0 += ks2; x1 += k0 + 5u;
#undef TFR
  o0 = x0; o1 = x1;
}

// random_bits(kperm, 32, (2^26,))[j], partitionable: counter=(0,j), bits=w0^w1
__device__ __forceinline__ uint32_t perm_bits(uint32_t kp0, uint32_t kp1, uint32_t j) {
  uint32_t w0, w1;
#if THREEFRY_PARTITIONABLE
  tf2x32(kp0, kp1, 0u, j, w0, w1);
  return w0 ^ w1;
#else
  uint32_t lo = j & 0x01FFFFFFu;
  tf2x32(kp0, kp1, lo, lo + 0x02000000u, w0, w1);
  return (j < 0x02000000u) ? w0 : w1;
#endif
}

// Stable argsort of 4 keys; scatter v[i] to output slot rank[i].
// Keys are bits>>9 (monotone-equal to the float uniforms, incl. exact ties).
__device__ __forceinline__ void shuffle4(const float v[4], const uint32_t s[4], float o[4]) {
  int r0 = 0, r1 = 0, r2 = 0, r3 = 0;
  if (s[1] < s[0]) r0++; else r1++;
  if (s[2] < s[0]) r0++; else r2++;
  if (s[3] < s[0]) r0++; else r3++;
  if (s[2] < s[1]) r1++; else r2++;
  if (s[3] < s[1]) r1++; else r3++;
  if (s[3] < s[2]) r2++; else r3++;
  o[0] = (r0 == 0) ? v[0] : (r1 == 0) ? v[1] : (r2 == 0) ? v[2] : v[3];
  o[1] = (r0 == 1) ? v[0] : (r1 == 1) ? v[1] : (r2 == 1) ? v[2] : v[3];
  o[2] = (r0 == 2) ? v[0] : (r1 == 2) ? v[1] : (r2 == 2) ? v[2] : v[3];
  o[3] = (r0 == 3) ? v[0] : (r1 == 3) ? v[1] : (r2 == 3) ? v[2] : v[3];
}

__global__ __launch_bounds__(256) void PatchShuffle_26869315404121_kernel(
    const float* __restrict__ x, float* __restrict__ out,
    uint32_t kp0, uint32_t kp1, uint32_t maskbits) {
  const uint32_t t   = blockIdx.x * 256u + threadIdx.x;  // [0, 2^23)
  const uint32_t gid = t << 1;                           // even patch index
  const uint32_t b   = gid >> 20;                        // sample
  const uint32_t wp  = gid & 127u;                       // even
  const uint32_t rest = gid >> 7;                        // (b*C+c)*Hp + hp
  const uint32_t base = rest * 512u + wp * 2u;           // row hp*2, col wp*2 (16B aligned)

  const float4 r0 = *reinterpret_cast<const float4*>(x + base);        // row 2*hp
  const float4 r1 = *reinterpret_cast<const float4*>(x + base + W_);   // row 2*hp+1
  float4* d0 = reinterpret_cast<float4*>(out + base);
  float4* d1 = reinterpret_cast<float4*>(out + base + W_);

  if (!((maskbits >> b) & 1u)) {   // block-uniform branch (512 patches/block)
    *d0 = r0; *d1 = r1;
    return;
  }

  // Shuffled sample: independent stable-argsort perm per patch.
  const uint32_t jbase = gid << 2;   // flat uniform index of patch gid, pixel 0
  uint32_t sA[4], sB[4];
#pragma unroll
  for (int p = 0; p < 4; ++p) sA[p] = perm_bits(kp0, kp1, jbase + (uint32_t)p) >> 9;
#pragma unroll
  for (int p = 0; p < 4; ++p) sB[p] = perm_bits(kp0, kp1, jbase + 4u + (uint32_t)p) >> 9;

  // patch pixel order p = ph*2+pw: [row0.x, row0.y, row1.x, row1.y]
  const float vA[4] = {r0.x, r0.y, r1.x, r1.y};   // patch gid   (cols 2wp,2wp+1)
  const float vB[4] = {r0.z, r0.w, r1.z, r1.w};   // patch gid+1 (cols 2wp+2,2wp+3)
  float oA[4], oB[4];
  shuffle4(vA, sA, oA);
  shuffle4(vB, sB, oB);
  *d0 = make_float4(oA[0], oA[1], oB[0], oB[1]);
  *d1 = make_float4(oA[2], oA[3], oB[2], oB[3]);
}

extern "C" void kernel_launch(void* const* d_in, const int* in_sizes, int n_in,
                              void* d_out, int out_size, void* d_ws, size_t ws_size,
                              hipStream_t stream) {
  const float* x = (const float*)d_in[0];
  float* out = (float*)d_out;

  // ---- host-side PRNG (pure arithmetic, deterministic, capture-safe) ----
  const uint32_t k0 = 0u, k1 = 42u;  // jax.random.key(42) -> [0, 42]
  uint32_t km0, km1, kp0, kp1;
#if THREEFRY_PARTITIONABLE
  tf2x32(k0, k1, 0u, 0u, km0, km1);  // split fold-like: kmask = TF(key,(0,0))
  tf2x32(k0, k1, 0u, 1u, kp0, kp1);  //                  kperm = TF(key,(0,1))
#else
  {
    uint32_t a0, a1, b0v, b1v;
    tf2x32(k0, k1, 0u, 2u, a0, a1);
    tf2x32(k0, k1, 1u, 3u, b0v, b1v);
    km0 = a0; km1 = b0v;
    kp0 = a1; kp1 = b1v;
  }
#endif

  uint32_t maskbits = 0u;
  for (uint32_t s = 0; s < 16u; ++s) {
    uint32_t w0, w1, bits;
#if THREEFRY_PARTITIONABLE
    tf2x32(km0, km1, 0u, s, w0, w1);
    bits = w0 ^ w1;
#else
    uint32_t i = s & 7u;
    tf2x32(km0, km1, i, i + 8u, w0, w1);
    bits = (s < 8u) ? w0 : w1;
#endif
    uint32_t fb = (bits >> 9) | 0x3F800000u;
    float u;
    std::memcpy(&u, &fb, sizeof(u));
    u -= 1.0f;                           // uniform in [0,1)
    if (u < 0.1f) maskbits |= (1u << s); // torch.rand(1) < shuffle_prob
  }

  PatchShuffle_26869315404121_kernel<<<NTHREAD / 256u, 256, 0, stream>>>(
      x, out, kp0, kp1, maskbits);
}